// Round 5
// baseline (1399.795 us; speedup 1.0000x reference)
//
#include <hip/hip_runtime.h>
#include <math.h>

typedef __attribute__((ext_vector_type(8))) short short8;
typedef __attribute__((ext_vector_type(4))) float f32x4;

#define INF 3.0e38f
#define NCELL1 32           // cells per axis
#define NCELL3 32768        // 32^3
#define NCHUNK 512          // prefix-scan chunks of 256 over 4*32768 cells

__device__ __forceinline__ unsigned short f2bf(float x) {
    union { float f; unsigned u; } v; v.f = x;
    unsigned r = v.u + 0x7FFF + ((v.u >> 16) & 1);   // RNE
    return (unsigned short)(r >> 16);
}

__device__ __forceinline__ int cellc(float v, float bmin, float invh) {
    int c = (int)floorf((v - bmin) * invh);
    return min(NCELL1 - 1, max(0, c));
}

// -------------------------------------------------- per-batch bbox of knowns
__global__ __launch_bounds__(256) void bbox_kernel(
    const float* __restrict__ kn, const int* __restrict__ kcnt, int B,
    float* __restrict__ bbox)   // [B][6] = xmin,ymin,zmin,xmax,ymax,zmax
{
    int b = blockIdx.x;
    int kstart = 0;
    for (int i = 0; i < b; i++) kstart += kcnt[i];
    int kend = kstart + kcnt[b];
    float mn[3] = {INF, INF, INF}, mx[3] = {-INF, -INF, -INF};
    for (int i = kstart + threadIdx.x; i < kend; i += 256) {
        for (int c = 0; c < 3; c++) {
            float v = kn[(size_t)i * 3 + c];
            mn[c] = fminf(mn[c], v);
            mx[c] = fmaxf(mx[c], v);
        }
    }
    __shared__ float smn[3][256], smx[3][256];
    for (int c = 0; c < 3; c++) { smn[c][threadIdx.x] = mn[c]; smx[c][threadIdx.x] = mx[c]; }
    __syncthreads();
    for (int off = 128; off > 0; off >>= 1) {
        if (threadIdx.x < off)
            for (int c = 0; c < 3; c++) {
                smn[c][threadIdx.x] = fminf(smn[c][threadIdx.x], smn[c][threadIdx.x + off]);
                smx[c][threadIdx.x] = fmaxf(smx[c][threadIdx.x], smx[c][threadIdx.x + off]);
            }
        __syncthreads();
    }
    if (threadIdx.x == 0)
        for (int c = 0; c < 3; c++) {
            bbox[b * 6 + c] = smn[c][0];
            bbox[b * 6 + 3 + c] = smx[c][0];
        }
}

// ----------------------------------------------------- histogram into cells
__global__ __launch_bounds__(256) void hist_kernel(
    const float* __restrict__ kn, const int* __restrict__ kcnt, int B, int M,
    const float* __restrict__ bbox, int* __restrict__ counts)
{
    int i = blockIdx.x * 256 + threadIdx.x;
    if (i >= M) return;
    int cum = 0, b = 0;
    for (int j = 0; j < B; j++) { int c = kcnt[j]; if (i >= cum) b = j; cum += c; }
    float x = kn[(size_t)i * 3 + 0], y = kn[(size_t)i * 3 + 1], z = kn[(size_t)i * 3 + 2];
    float bx = bbox[b * 6 + 0], by = bbox[b * 6 + 1], bz = bbox[b * 6 + 2];
    float ix = (float)NCELL1 / fmaxf(bbox[b * 6 + 3] - bx, 1e-6f);
    float iy = (float)NCELL1 / fmaxf(bbox[b * 6 + 4] - by, 1e-6f);
    float iz = (float)NCELL1 / fmaxf(bbox[b * 6 + 5] - bz, 1e-6f);
    int cx = cellc(x, bx, ix), cy = cellc(y, by, iy), cz = cellc(z, bz, iz);
    int cid = (b << 15) + (cz << 10) + (cy << 5) + cx;
    atomicAdd(&counts[cid], 1);
}

// ------------------------------------- hierarchical exclusive prefix scan --
__global__ __launch_bounds__(256) void scan1_kernel(
    const int* __restrict__ counts, int* __restrict__ excl, int* __restrict__ bsum)
{
    __shared__ int sh[256];
    int tid = threadIdx.x;
    int g = blockIdx.x * 256 + tid;
    int v = counts[g];
    sh[tid] = v;
    __syncthreads();
    int x = v;
    for (int off = 1; off < 256; off <<= 1) {
        int y = (tid >= off) ? sh[tid - off] : 0;
        __syncthreads();
        x += y;
        sh[tid] = x;
        __syncthreads();
    }
    excl[g] = x - v;
    if (tid == 255) bsum[blockIdx.x] = x;
}

__global__ __launch_bounds__(512) void scan2_kernel(
    const int* __restrict__ bsum, int* __restrict__ bbase, int* __restrict__ fs)
{
    __shared__ int sh[512];
    int tid = threadIdx.x;
    int v = bsum[tid];
    sh[tid] = v;
    __syncthreads();
    int x = v;
    for (int off = 1; off < 512; off <<= 1) {
        int y = (tid >= off) ? sh[tid - off] : 0;
        __syncthreads();
        x += y;
        sh[tid] = x;
        __syncthreads();
    }
    bbase[tid] = x - v;
    if (tid == 511) fs[NCHUNK * 256] = x;   // sentinel: grand total
}

__global__ __launch_bounds__(256) void fixup_kernel(
    const int* __restrict__ excl, const int* __restrict__ bbase, int* __restrict__ fs)
{
    int g = blockIdx.x * 256 + threadIdx.x;
    fs[g] = excl[g] + bbase[g >> 8];
}

// ------------------------------------------- scatter points into cell order
__global__ __launch_bounds__(256) void scatter_kernel(
    const float* __restrict__ kn, const int* __restrict__ kcnt, int B, int M,
    const float* __restrict__ bbox, const int* __restrict__ fs,
    int* __restrict__ cursor, float4* __restrict__ pts)
{
    int i = blockIdx.x * 256 + threadIdx.x;
    if (i >= M) return;
    int cum = 0, b = 0;
    for (int j = 0; j < B; j++) { int c = kcnt[j]; if (i >= cum) b = j; cum += c; }
    float x = kn[(size_t)i * 3 + 0], y = kn[(size_t)i * 3 + 1], z = kn[(size_t)i * 3 + 2];
    float bx = bbox[b * 6 + 0], by = bbox[b * 6 + 1], bz = bbox[b * 6 + 2];
    float ix = (float)NCELL1 / fmaxf(bbox[b * 6 + 3] - bx, 1e-6f);
    float iy = (float)NCELL1 / fmaxf(bbox[b * 6 + 4] - by, 1e-6f);
    float iz = (float)NCELL1 / fmaxf(bbox[b * 6 + 5] - bz, 1e-6f);
    int cx = cellc(x, bx, ix), cy = cellc(y, by, iy), cz = cellc(z, bz, iz);
    int cid = (b << 15) + (cz << 10) + (cy << 5) + cx;
    int slot = atomicAdd(&cursor[cid], 1);
    float4 r; r.x = x; r.y = y; r.z = z; r.w = __int_as_float(i);
    pts[fs[cid] + slot] = r;
}

// ------------------------------------------------ grid-accelerated exact 3NN
// Ring-ρ cells lie ≥ (ρ-1)*hmin from the query (query clamped into its cell;
// out-of-box points clamped into edge cells — both directions conservative).
// Inserts via exact u64 (f32bits(d2)<<32 | idx) lex keys == top_k semantics.
__global__ __launch_bounds__(256) void knn_grid_kernel(
    const float* __restrict__ unk, const int* __restrict__ ucnt, int B, int N,
    const float* __restrict__ bbox, const int* __restrict__ fs,
    const float4* __restrict__ pts,
    float* __restrict__ wgt, int* __restrict__ idxo)
{
    int p = blockIdx.x * 256 + threadIdx.x;
    if (p >= N) return;
    int cum = 0, b = 0;
    for (int j = 0; j < B; j++) { int c = ucnt[j]; if (p >= cum) b = j; cum += c; }

    float qx = unk[(size_t)p * 3 + 0], qy = unk[(size_t)p * 3 + 1], qz = unk[(size_t)p * 3 + 2];
    float bx = bbox[b * 6 + 0], by = bbox[b * 6 + 1], bz = bbox[b * 6 + 2];
    float ex = fmaxf(bbox[b * 6 + 3] - bx, 1e-6f);
    float ey = fmaxf(bbox[b * 6 + 4] - by, 1e-6f);
    float ez = fmaxf(bbox[b * 6 + 5] - bz, 1e-6f);
    float ix = (float)NCELL1 / ex, iy = (float)NCELL1 / ey, iz = (float)NCELL1 / ez;
    float hmin = fminf(fminf(ex, ey), ez) * (1.0f / NCELL1);
    int cx = cellc(qx, bx, ix), cy = cellc(qy, by, iy), cz = cellc(qz, bz, iz);
    int cbase = b << 15;

    unsigned long long s0 = ~0ULL, s1 = ~0ULL, s2 = ~0ULL;
    auto insK = [&](unsigned long long k) {
        bool c0 = k < s0;
        unsigned long long t0 = c0 ? k : s0;
        unsigned long long t1 = c0 ? s0 : k;
        bool c1 = t1 < s1;
        unsigned long long u0 = c1 ? t1 : s1;
        unsigned long long u1 = c1 ? s1 : t1;
        s0 = t0; s1 = u0;
        s2 = u1 < s2 ? u1 : s2;
    };

    for (int rho = 0; rho < NCELL1; rho++) {
        if (rho >= 2) {
            float bnd = (float)(rho - 1) * hmin;
            float d2v = __uint_as_float((unsigned)(s2 >> 32));  // NaN if unset -> no break
            if (d2v < bnd * bnd) break;
        }
        int zlo = max(cz - rho, 0), zhi = min(cz + rho, NCELL1 - 1);
        for (int z = zlo; z <= zhi; z++) {
            bool zface = (z == cz - rho) || (z == cz + rho);
            int ylo = max(cy - rho, 0), yhi = min(cy + rho, NCELL1 - 1);
            for (int y = ylo; y <= yhi; y++) {
                bool yface = (y == cy - rho) || (y == cy + rho);
                int xlo, xhi, xstep;
                if (zface || yface) { xlo = max(cx - rho, 0); xhi = min(cx + rho, NCELL1 - 1); xstep = 1; }
                else                { xlo = cx - rho; xhi = cx + rho; xstep = 2 * rho; }
                for (int x = xlo; x <= xhi; x += xstep) {
                    if (x < 0 || x > NCELL1 - 1) continue;
                    int cid = cbase + (z << 10) + (y << 5) + x;
                    int st = fs[cid], en = fs[cid + 1];
                    for (int t = st; t < en; t++) {
                        float4 kp = pts[t];
                        float dx = qx - kp.x, dy = qy - kp.y, dz = qz - kp.z;
                        float e = dx * dx + dy * dy + dz * dz;
                        unsigned long long key =
                            ((unsigned long long)__float_as_uint(e) << 32)
                            | (unsigned)__float_as_int(kp.w);
                        insK(key);
                    }
                }
            }
        }
    }

    float d0 = __uint_as_float((unsigned)(s0 >> 32));
    float d1 = __uint_as_float((unsigned)(s1 >> 32));
    float d2 = __uint_as_float((unsigned)(s2 >> 32));
    float r0 = 1.0f / (d0 + 1e-8f);
    float r1 = 1.0f / (d1 + 1e-8f);
    float r2 = 1.0f / (d2 + 1e-8f);
    float rs = 1.0f / (r0 + r1 + r2);
    wgt[p * 3 + 0] = r0 * rs;
    wgt[p * 3 + 1] = r1 * rs;
    wgt[p * 3 + 2] = r2 * rs;
    idxo[p * 3 + 0] = (int)(unsigned)s0;
    idxo[p * 3 + 1] = (int)(unsigned)s1;
    idxo[p * 3 + 2] = (int)(unsigned)s2;
}

// --------------------------- build A1 = [interp | ufeat] as bf16 [N,384] --
__global__ __launch_bounds__(256) void build_a1_kernel(
    const float* __restrict__ wgt, const int* __restrict__ idxv,
    const float* __restrict__ kfeat, const float* __restrict__ ufeat,
    unsigned short* __restrict__ A1, int N)
{
    int t = blockIdx.x * 256 + threadIdx.x;
    int p = t >> 6, c4 = t & 63;
    if (p >= N) return;
    float w0 = wgt[p * 3 + 0], w1 = wgt[p * 3 + 1], w2 = wgt[p * 3 + 2];
    int j0 = idxv[p * 3 + 0], j1 = idxv[p * 3 + 1], j2 = idxv[p * 3 + 2];
    float4 v0 = ((const float4*)(kfeat + (size_t)j0 * 256))[c4];
    float4 v1 = ((const float4*)(kfeat + (size_t)j1 * 256))[c4];
    float4 v2 = ((const float4*)(kfeat + (size_t)j2 * 256))[c4];
    ushort4 ob;
    ob.x = f2bf(v0.x * w0 + v1.x * w1 + v2.x * w2);
    ob.y = f2bf(v0.y * w0 + v1.y * w1 + v2.y * w2);
    ob.z = f2bf(v0.z * w0 + v1.z * w1 + v2.z * w2);
    ob.w = f2bf(v0.w * w0 + v1.w * w1 + v2.w * w2);
    *(ushort4*)(A1 + (size_t)p * 384 + c4 * 4) = ob;
    float2 u = ((const float2*)(ufeat + (size_t)p * 128))[c4];
    ushort2 ub; ub.x = f2bf(u.x); ub.y = f2bf(u.y);
    *(ushort2*)(A1 + (size_t)p * 384 + 256 + c4 * 2) = ub;
}

// ------------------------------------------------ weight fp32->bf16 conv --
__global__ __launch_bounds__(256) void wconv_kernel(
    const float* __restrict__ W1, const float* __restrict__ W2,
    unsigned short* __restrict__ W1b, unsigned short* __restrict__ W2b,
    int n1, int n2)
{
    int i = blockIdx.x * 256 + threadIdx.x;
    if (i < n1) W1b[i] = f2bf(W1[i]);
    int j = i - n1;
    if (j >= 0 && j < n2) W2b[j] = f2bf(W2[j]);
}

// -------------------------------------------------------- bf16 MFMA GEMM --
// C[N,256] = A[N,K] x W[256,K]^T.  128x128 tile, BK=32, 16x16x32 MFMA.
// MODE 0: A is bf16 [N,K].
// MODE 1: A is fp32 [N,K]; staging applies relu(A*scale+shift) then bf16.
// Fused epilogue: per-block column sum/sumsq of C -> global atomics (BN stats).
template <int K, int MODE>
__global__ __launch_bounds__(256) void gemm_bf16_kernel(
    const void* __restrict__ Av, const unsigned short* __restrict__ W,
    const float* __restrict__ scale, const float* __restrict__ shift,
    float* __restrict__ C, float* __restrict__ gsum, float* __restrict__ gsq)
{
    __shared__ unsigned short As[128 * 40];
    __shared__ unsigned short Bs[128 * 40];
    __shared__ float colsum[128];
    __shared__ float colsq[128];

    int tid = threadIdx.x;
    int w = tid >> 6, lane = tid & 63;
    int r = w >> 1, cq = w & 1;
    int m16 = lane & 15, q = lane >> 4;
    int bm = blockIdx.x * 128, bn = blockIdx.y * 128;

    f32x4 acc[4][4];
#pragma unroll
    for (int i = 0; i < 4; i++)
#pragma unroll
        for (int j = 0; j < 4; j++) acc[i][j] = (f32x4){0.f, 0.f, 0.f, 0.f};

#pragma unroll
    for (int k0 = 0; k0 < K; k0 += 32) {
        __syncthreads();
#pragma unroll
        for (int i = 0; i < 2; i++) {
            int id = tid + i * 256;
            int row = id >> 2, kc = (id & 3) * 8;
            if (MODE == 0) {
                *(short8*)&As[row * 40 + kc] =
                    *(const short8*)((const unsigned short*)Av +
                                     (size_t)(bm + row) * K + k0 + kc);
            } else {
                const float* Af = (const float*)Av;
                float4 v0 = *(const float4*)(Af + (size_t)(bm + row) * K + k0 + kc);
                float4 v1 = *(const float4*)(Af + (size_t)(bm + row) * K + k0 + kc + 4);
                float4 s0 = *(const float4*)(scale + k0 + kc);
                float4 s1 = *(const float4*)(scale + k0 + kc + 4);
                float4 t0 = *(const float4*)(shift + k0 + kc);
                float4 t1 = *(const float4*)(shift + k0 + kc + 4);
                ushort4 o0, o1;
                o0.x = f2bf(fmaxf(v0.x * s0.x + t0.x, 0.f));
                o0.y = f2bf(fmaxf(v0.y * s0.y + t0.y, 0.f));
                o0.z = f2bf(fmaxf(v0.z * s0.z + t0.z, 0.f));
                o0.w = f2bf(fmaxf(v0.w * s0.w + t0.w, 0.f));
                o1.x = f2bf(fmaxf(v1.x * s1.x + t1.x, 0.f));
                o1.y = f2bf(fmaxf(v1.y * s1.y + t1.y, 0.f));
                o1.z = f2bf(fmaxf(v1.z * s1.z + t1.z, 0.f));
                o1.w = f2bf(fmaxf(v1.w * s1.w + t1.w, 0.f));
                *(ushort4*)&As[row * 40 + kc] = o0;
                *(ushort4*)&As[row * 40 + kc + 4] = o1;
            }
            *(short8*)&Bs[row * 40 + kc] =
                *(const short8*)(W + (size_t)(bn + row) * K + k0 + kc);
        }
        __syncthreads();

        short8 af[4], bf[4];
#pragma unroll
        for (int sub = 0; sub < 4; sub++) {
            af[sub] = *(const short8*)&As[(r * 64 + sub * 16 + m16) * 40 + q * 8];
            bf[sub] = *(const short8*)&Bs[(cq * 64 + sub * 16 + m16) * 40 + q * 8];
        }
#pragma unroll
        for (int sm = 0; sm < 4; sm++)
#pragma unroll
            for (int sn = 0; sn < 4; sn++)
                acc[sm][sn] = __builtin_amdgcn_mfma_f32_16x16x32_bf16(
                    af[sm], bf[sn], acc[sm][sn], 0, 0, 0);
    }

    int row0 = bm + r * 64 + q * 4;
    int col0 = bn + cq * 64 + m16;
#pragma unroll
    for (int sm = 0; sm < 4; sm++)
#pragma unroll
        for (int sn = 0; sn < 4; sn++) {
            f32x4 v = acc[sm][sn];
#pragma unroll
            for (int reg = 0; reg < 4; reg++)
                C[(size_t)(row0 + sm * 16 + reg) * 256 + col0 + sn * 16] = v[reg];
        }

    // ---- fused BN stats: per-block column sums of the 128x128 C tile ----
    __syncthreads();
    if (tid < 128) { colsum[tid] = 0.f; colsq[tid] = 0.f; }
    __syncthreads();
#pragma unroll
    for (int sn = 0; sn < 4; sn++) {
        float sacc = 0.f, qacc = 0.f;
#pragma unroll
        for (int sm = 0; sm < 4; sm++) {
            f32x4 v = acc[sm][sn];
#pragma unroll
            for (int reg = 0; reg < 4; reg++) {
                sacc += v[reg];
                qacc += v[reg] * v[reg];
            }
        }
        int lc = cq * 64 + sn * 16 + m16;
        atomicAdd(&colsum[lc], sacc);
        atomicAdd(&colsq[lc], qacc);
    }
    __syncthreads();
    if (tid < 128) {
        atomicAdd(&gsum[bn + tid], colsum[tid]);
        atomicAdd(&gsq[bn + tid], colsq[tid]);
    }
}

__global__ void bn_finalize_kernel(
    const float* __restrict__ sum, const float* __restrict__ sumsq,
    const float* __restrict__ g, const float* __restrict__ bta, float invN,
    float* __restrict__ scale, float* __restrict__ shift)
{
    int c = threadIdx.x;
    float mean = sum[c] * invN;
    float var = sumsq[c] * invN - mean * mean;   // biased, matches torch BN
    float sc = g[c] * rsqrtf(var + 1e-5f);
    scale[c] = sc;
    shift[c] = bta[c] - mean * sc;
}

// ----------------------------- final: h2(ws) -> bn+relu -> d_out ----------
__global__ __launch_bounds__(256) void final_act_kernel(
    const float* __restrict__ h2, const float* __restrict__ scale,
    const float* __restrict__ shift, float* __restrict__ out, int total4)
{
    int i = blockIdx.x * 256 + threadIdx.x;
    if (i >= total4) return;
    int c4 = i & 63;
    float4 v = ((const float4*)h2)[i];
    float4 s = ((const float4*)scale)[c4];
    float4 t = ((const float4*)shift)[c4];
    float4 o;
    o.x = fmaxf(v.x * s.x + t.x, 0.0f);
    o.y = fmaxf(v.y * s.y + t.y, 0.0f);
    o.z = fmaxf(v.z * s.z + t.z, 0.0f);
    o.w = fmaxf(v.w * s.w + t.w, 0.0f);
    ((float4*)out)[i] = o;
}

// ------------------------------------------------------------------ launch --
extern "C" void kernel_launch(void* const* d_in, const int* in_sizes, int n_in,
                              void* d_out, int out_size, void* d_ws, size_t ws_size,
                              hipStream_t stream)
{
    const float* unknown = (const float*)d_in[0];
    const int*   ucnt    = (const int*)d_in[1];
    const float* known   = (const float*)d_in[2];
    const int*   kcnt    = (const int*)d_in[3];
    const float* ufeat   = (const float*)d_in[4];
    const float* kfeat   = (const float*)d_in[5];
    const float* W1      = (const float*)d_in[6];
    const float* g1      = (const float*)d_in[7];
    const float* b1      = (const float*)d_in[8];
    const float* W2      = (const float*)d_in[9];
    const float* g2      = (const float*)d_in[10];
    const float* b2      = (const float*)d_in[11];

    int N = in_sizes[0] / 3;        // 65536
    int B = in_sizes[1];            // 4
    int M = in_sizes[2] / 3;        // 16384

    char* ws = (char*)d_ws;
    size_t off = 0;
    float* wgt = (float*)(ws + off);            off += (size_t)N * 3 * 4;
    int*   idxb = (int*)(ws + off);             off += (size_t)N * 3 * 4;
    float* stats = (float*)(ws + off);          off += 8 * 256 * 4;
    float* sum1 = stats,         *sq1 = stats + 256;
    float* scale1 = stats + 512, *shift1 = stats + 768;
    float* sum2 = stats + 1024,  *sq2 = stats + 1280;
    float* scale2 = stats + 1536, *shift2 = stats + 1792;
    float* bbox = (float*)(ws + off);           off += 64 * 4;  // 4*6 padded
    unsigned short* W1b = (unsigned short*)(ws + off);  off += 256 * 384 * 2;
    unsigned short* W2b = (unsigned short*)(ws + off);  off += 256 * 256 * 2;
    off = (off + 255) & ~(size_t)255;

    // big region: grid-build buffers (dead before build_a1) alias A1, which
    // is itself dead before h2 is written. Peak ws ~69MB (r2-proven size).
    char* big = ws + off;
    int*  counts = (int*)big;                                   // 512KB
    int*  cursor = (int*)(big + 512 * 1024);                    // 512KB (adjacent: one memset)
    int*  excl   = (int*)(big + 1024 * 1024);                   // 512KB
    int*  fs     = (int*)(big + 1536 * 1024);                   // 512KB+4
    int*  bsum   = (int*)(big + 2052 * 1024);                   // 2KB
    int*  bbase  = (int*)(big + 2056 * 1024);                   // 2KB
    float4* pts  = (float4*)(big + 2060 * 1024);                // 256KB
    unsigned short* A1 = (unsigned short*)big;                  // N*384 bf16
    float* h2 = (float*)big;                                    // N*256 fp32
    float* h1 = (float*)d_out;

    hipMemsetAsync(stats, 0, 8 * 256 * 4, stream);
    hipMemsetAsync(counts, 0, 2 * 512 * 1024, stream);          // counts + cursor

    bbox_kernel<<<B, 256, 0, stream>>>(known, kcnt, B, bbox);
    hist_kernel<<<(M + 255) / 256, 256, 0, stream>>>(known, kcnt, B, M, bbox, counts);
    scan1_kernel<<<NCHUNK, 256, 0, stream>>>(counts, excl, bsum);
    scan2_kernel<<<1, 512, 0, stream>>>(bsum, bbase, fs);
    fixup_kernel<<<NCHUNK, 256, 0, stream>>>(excl, bbase, fs);
    scatter_kernel<<<(M + 255) / 256, 256, 0, stream>>>(known, kcnt, B, M, bbox,
                                                        fs, cursor, pts);
    knn_grid_kernel<<<N / 256, 256, 0, stream>>>(unknown, ucnt, B, N, bbox, fs,
                                                 pts, wgt, idxb);
    wconv_kernel<<<(256 * 384 + 256 * 256 + 255) / 256, 256, 0, stream>>>(
        W1, W2, W1b, W2b, 256 * 384, 256 * 256);
    build_a1_kernel<<<N / 4, 256, 0, stream>>>(wgt, idxb, kfeat, ufeat, A1, N);
    gemm_bf16_kernel<384, 0><<<dim3(N / 128, 2), 256, 0, stream>>>(
        A1, W1b, nullptr, nullptr, h1, sum1, sq1);
    bn_finalize_kernel<<<1, 256, 0, stream>>>(sum1, sq1, g1, b1, 1.0f / N,
                                              scale1, shift1);
    gemm_bf16_kernel<256, 1><<<dim3(N / 128, 2), 256, 0, stream>>>(
        h1, W2b, scale1, shift1, h2, sum2, sq2);
    bn_finalize_kernel<<<1, 256, 0, stream>>>(sum2, sq2, g2, b2, 1.0f / N,
                                              scale2, shift2);
    final_act_kernel<<<N / 4, 256, 0, stream>>>(h2, scale2, shift2,
                                                (float*)d_out, N * 64);
}

// Round 7
// 413.611 us; speedup vs baseline: 3.3843x; 3.3843x over previous
//
#include <hip/hip_runtime.h>
#include <math.h>

typedef __attribute__((ext_vector_type(8))) short short8;
typedef __attribute__((ext_vector_type(4))) float f32x4;

#define INF 3.0e38f

__device__ __forceinline__ unsigned short f2bf(float x) {
    union { float f; unsigned u; } v; v.f = x;
    unsigned r = v.u + 0x7FFF + ((v.u >> 16) & 1);   // RNE
    return (unsigned short)(r >> 16);
}

// Pinned distance: identical FP contraction in both passes (bit-exact match
// between pass-1 threshold and pass-2 rescan is REQUIRED for correctness).
__device__ __forceinline__ float dist2(float ux, float uy, float uz, float4 k) {
    float dx = ux - k.x, dy = uy - k.y, dz = uz - k.z;
    return __builtin_fmaf(dx, dx, __builtin_fmaf(dy, dy, dz * dz));
}

// ---------------------------------------------------------------- 3-NN ----
// Two-pass: pass 1 finds top-3 DISTANCE VALUES with a pure min/max network
// (no compares, no vcc traffic, ~11 instr/cand); waves merge -> global 3rd-
// smallest value thr per point; pass 2 rescans and rare-inserts exact u64
// (f32bits(d2)<<32 | idx) lex keys only when min4(e) <= thr (~17% of wave-
// steps). Final u64 merge == lax.top_k (d, idx) semantics, bit-exact.
// 1024 blocks x 256 thr; block = 64 points, 4 waves scan quarter ranges of
// the LDS-staged knowns (wave-uniform broadcast reads).
__global__ __launch_bounds__(256) void knn3_kernel(
    const float* __restrict__ unk, const float* __restrict__ kn,
    const int* __restrict__ ucnt, const int* __restrict__ kcnt,
    int B, int N, float* __restrict__ wgt, int* __restrict__ idxo)
{
    __shared__ float4 kxyz[1024];
    __shared__ float md[4][64][3];
    __shared__ float d2g[64];
    __shared__ unsigned long long mk[4][64][3];

    int tid = threadIdx.x;
    int s = tid >> 6;
    int lane = tid & 63;
    int pbase = blockIdx.x * 64;
    int p = pbase + lane;

    int cum = 0, bb = 0;
    for (int i = 0; i < B; i++) { int c = ucnt[i]; if (pbase >= cum) bb = i; cum += c; }
    int kstart = 0;
    for (int i = 0; i < bb; i++) kstart += kcnt[i];
    int kend = kstart + kcnt[bb];

    float ux = unk[p * 3 + 0], uy = unk[p * 3 + 1], uz = unk[p * 3 + 2];

    float d0 = INF, d1 = INF, d2 = INF;
    // 2 max + 3 min, no compares (d0<=d1<=d2 invariant)
    auto upd = [&](float e) {
        float m0 = fmaxf(e, d0);
        float m1 = fmaxf(e, d1);
        d0 = fminf(e, d0);
        d1 = fminf(m0, d1);
        d2 = fminf(m1, d2);
    };

    // ----------------- pass 1: top-3 values over own quarter -----------------
    for (int t0g = kstart; t0g < kend; t0g += 1024) {
        int cnt = min(1024, kend - t0g);
        __syncthreads();
        for (int f = tid; f < cnt * 3; f += 256) {
            int pt = f / 3, c = f - pt * 3;
            ((float*)&kxyz[pt])[c] = kn[(size_t)(t0g + pt) * 3 + c];
        }
        __syncthreads();

        int qlen = cnt >> 2;
        int base = s * qlen;
        for (int i = 0; i < qlen; i += 4) {
            float e0 = dist2(ux, uy, uz, kxyz[base + i]);
            float e1 = dist2(ux, uy, uz, kxyz[base + i + 1]);
            float e2 = dist2(ux, uy, uz, kxyz[base + i + 2]);
            float e3 = dist2(ux, uy, uz, kxyz[base + i + 3]);
            upd(e0); upd(e1); upd(e2); upd(e3);
        }
    }

    md[s][lane][0] = d0; md[s][lane][1] = d1; md[s][lane][2] = d2;
    __syncthreads();
    if (tid < 64) {
        float v0 = INF, v1 = INF, v2 = INF;
#pragma unroll
        for (int w = 0; w < 4; w++)
#pragma unroll
            for (int k = 0; k < 3; k++) {
                float e = md[w][tid][k];
                float m0 = fmaxf(e, v0);
                float m1 = fmaxf(e, v1);
                v0 = fminf(e, v0);
                v1 = fminf(m0, v1);
                v2 = fminf(m1, v2);
            }
        d2g[tid] = v2;
    }
    __syncthreads();
    float thr = d2g[lane];

    // ----------------- pass 2: collect indices (rare path) ------------------
    unsigned long long s0 = ~0ULL, s1 = ~0ULL, s2 = ~0ULL;
    auto insK = [&](unsigned long long k) {
        bool c0 = k < s0;
        unsigned long long t0 = c0 ? k : s0;
        unsigned long long t1 = c0 ? s0 : k;
        bool c1 = t1 < s1;
        unsigned long long u0 = c1 ? t1 : s1;
        unsigned long long u1 = c1 ? s1 : t1;
        s0 = t0; s1 = u0;
        s2 = u1 < s2 ? u1 : s2;
    };
    auto mkkey = [](float e, int gj) {
        return ((unsigned long long)__float_as_uint(e) << 32) | (unsigned)gj;
    };

    for (int t0g = kstart; t0g < kend; t0g += 1024) {
        int cnt = min(1024, kend - t0g);
        __syncthreads();
        for (int f = tid; f < cnt * 3; f += 256) {
            int pt = f / 3, c = f - pt * 3;
            ((float*)&kxyz[pt])[c] = kn[(size_t)(t0g + pt) * 3 + c];
        }
        __syncthreads();

        int qlen = cnt >> 2;
        int base = s * qlen;
        for (int i = 0; i < qlen; i += 4) {
            float e0 = dist2(ux, uy, uz, kxyz[base + i]);
            float e1 = dist2(ux, uy, uz, kxyz[base + i + 1]);
            float e2 = dist2(ux, uy, uz, kxyz[base + i + 2]);
            float e3 = dist2(ux, uy, uz, kxyz[base + i + 3]);
            float m4 = fminf(fminf(e0, e1), fminf(e2, e3));
            if (m4 <= thr) {                 // rare: ~3 hits/lane over full scan
                int gj = t0g + base + i;
                insK(mkkey(e0, gj + 0));
                insK(mkkey(e1, gj + 1));
                insK(mkkey(e2, gj + 2));
                insK(mkkey(e3, gj + 3));
            }
        }
    }

    mk[s][lane][0] = s0; mk[s][lane][1] = s1; mk[s][lane][2] = s2;
    __syncthreads();

    if (tid < 64) {
        s0 = s1 = s2 = ~0ULL;
#pragma unroll
        for (int qq = 0; qq < 4; qq++)
#pragma unroll
            for (int kk = 0; kk < 3; kk++)
                insK(mk[qq][tid][kk]);

        float dd0 = __uint_as_float((unsigned)(s0 >> 32));
        float dd1 = __uint_as_float((unsigned)(s1 >> 32));
        float dd2 = __uint_as_float((unsigned)(s2 >> 32));
        float r0 = 1.0f / (dd0 + 1e-8f);
        float r1 = 1.0f / (dd1 + 1e-8f);
        float r2 = 1.0f / (dd2 + 1e-8f);
        float rs = 1.0f / (r0 + r1 + r2);
        int pp = pbase + tid;
        wgt[pp * 3 + 0] = r0 * rs;
        wgt[pp * 3 + 1] = r1 * rs;
        wgt[pp * 3 + 2] = r2 * rs;
        idxo[pp * 3 + 0] = (int)(unsigned)s0;
        idxo[pp * 3 + 1] = (int)(unsigned)s1;
        idxo[pp * 3 + 2] = (int)(unsigned)s2;
    }
}

// --------------------------- build A1 = [interp | ufeat] as bf16 [N,384] --
__global__ __launch_bounds__(256) void build_a1_kernel(
    const float* __restrict__ wgt, const int* __restrict__ idxv,
    const float* __restrict__ kfeat, const float* __restrict__ ufeat,
    unsigned short* __restrict__ A1, int N)
{
    int t = blockIdx.x * 256 + threadIdx.x;
    int p = t >> 6, c4 = t & 63;
    if (p >= N) return;
    float w0 = wgt[p * 3 + 0], w1 = wgt[p * 3 + 1], w2 = wgt[p * 3 + 2];
    int j0 = idxv[p * 3 + 0], j1 = idxv[p * 3 + 1], j2 = idxv[p * 3 + 2];
    float4 v0 = ((const float4*)(kfeat + (size_t)j0 * 256))[c4];
    float4 v1 = ((const float4*)(kfeat + (size_t)j1 * 256))[c4];
    float4 v2 = ((const float4*)(kfeat + (size_t)j2 * 256))[c4];
    ushort4 ob;
    ob.x = f2bf(v0.x * w0 + v1.x * w1 + v2.x * w2);
    ob.y = f2bf(v0.y * w0 + v1.y * w1 + v2.y * w2);
    ob.z = f2bf(v0.z * w0 + v1.z * w1 + v2.z * w2);
    ob.w = f2bf(v0.w * w0 + v1.w * w1 + v2.w * w2);
    *(ushort4*)(A1 + (size_t)p * 384 + c4 * 4) = ob;
    float2 u = ((const float2*)(ufeat + (size_t)p * 128))[c4];
    ushort2 ub; ub.x = f2bf(u.x); ub.y = f2bf(u.y);
    *(ushort2*)(A1 + (size_t)p * 384 + 256 + c4 * 2) = ub;
}

// ------------------------------------------------ weight fp32->bf16 conv --
__global__ __launch_bounds__(256) void wconv_kernel(
    const float* __restrict__ W1, const float* __restrict__ W2,
    unsigned short* __restrict__ W1b, unsigned short* __restrict__ W2b,
    int n1, int n2)
{
    int i = blockIdx.x * 256 + threadIdx.x;
    if (i < n1) W1b[i] = f2bf(W1[i]);
    int j = i - n1;
    if (j >= 0 && j < n2) W2b[j] = f2bf(W2[j]);
}

// -------------------------------------------------------- bf16 MFMA GEMM --
// C[N,256] = A[N,K] x W[256,K]^T.  128x128 tile, BK=32, 16x16x32 MFMA.
// MODE 0: A is bf16 [N,K].
// MODE 1: A is fp32 [N,K]; staging applies relu(A*scale+shift) then bf16.
// Fused epilogue: per-block column sum/sumsq of C -> global atomics (BN stats).
template <int K, int MODE>
__global__ __launch_bounds__(256) void gemm_bf16_kernel(
    const void* __restrict__ Av, const unsigned short* __restrict__ W,
    const float* __restrict__ scale, const float* __restrict__ shift,
    float* __restrict__ C, float* __restrict__ gsum, float* __restrict__ gsq)
{
    __shared__ unsigned short As[128 * 40];
    __shared__ unsigned short Bs[128 * 40];
    __shared__ float colsum[128];
    __shared__ float colsq[128];

    int tid = threadIdx.x;
    int w = tid >> 6, lane = tid & 63;
    int r = w >> 1, cq = w & 1;
    int m16 = lane & 15, q = lane >> 4;
    int bm = blockIdx.x * 128, bn = blockIdx.y * 128;

    f32x4 acc[4][4];
#pragma unroll
    for (int i = 0; i < 4; i++)
#pragma unroll
        for (int j = 0; j < 4; j++) acc[i][j] = (f32x4){0.f, 0.f, 0.f, 0.f};

#pragma unroll
    for (int k0 = 0; k0 < K; k0 += 32) {
        __syncthreads();
#pragma unroll
        for (int i = 0; i < 2; i++) {
            int id = tid + i * 256;
            int row = id >> 2, kc = (id & 3) * 8;
            if (MODE == 0) {
                *(short8*)&As[row * 40 + kc] =
                    *(const short8*)((const unsigned short*)Av +
                                     (size_t)(bm + row) * K + k0 + kc);
            } else {
                const float* Af = (const float*)Av;
                float4 v0 = *(const float4*)(Af + (size_t)(bm + row) * K + k0 + kc);
                float4 v1 = *(const float4*)(Af + (size_t)(bm + row) * K + k0 + kc + 4);
                float4 s0 = *(const float4*)(scale + k0 + kc);
                float4 s1 = *(const float4*)(scale + k0 + kc + 4);
                float4 t0 = *(const float4*)(shift + k0 + kc);
                float4 t1 = *(const float4*)(shift + k0 + kc + 4);
                ushort4 o0, o1;
                o0.x = f2bf(fmaxf(v0.x * s0.x + t0.x, 0.f));
                o0.y = f2bf(fmaxf(v0.y * s0.y + t0.y, 0.f));
                o0.z = f2bf(fmaxf(v0.z * s0.z + t0.z, 0.f));
                o0.w = f2bf(fmaxf(v0.w * s0.w + t0.w, 0.f));
                o1.x = f2bf(fmaxf(v1.x * s1.x + t1.x, 0.f));
                o1.y = f2bf(fmaxf(v1.y * s1.y + t1.y, 0.f));
                o1.z = f2bf(fmaxf(v1.z * s1.z + t1.z, 0.f));
                o1.w = f2bf(fmaxf(v1.w * s1.w + t1.w, 0.f));
                *(ushort4*)&As[row * 40 + kc] = o0;
                *(ushort4*)&As[row * 40 + kc + 4] = o1;
            }
            *(short8*)&Bs[row * 40 + kc] =
                *(const short8*)(W + (size_t)(bn + row) * K + k0 + kc);
        }
        __syncthreads();

        short8 af[4], bf[4];
#pragma unroll
        for (int sub = 0; sub < 4; sub++) {
            af[sub] = *(const short8*)&As[(r * 64 + sub * 16 + m16) * 40 + q * 8];
            bf[sub] = *(const short8*)&Bs[(cq * 64 + sub * 16 + m16) * 40 + q * 8];
        }
#pragma unroll
        for (int sm = 0; sm < 4; sm++)
#pragma unroll
            for (int sn = 0; sn < 4; sn++)
                acc[sm][sn] = __builtin_amdgcn_mfma_f32_16x16x32_bf16(
                    af[sm], bf[sn], acc[sm][sn], 0, 0, 0);
    }

    int row0 = bm + r * 64 + q * 4;
    int col0 = bn + cq * 64 + m16;
#pragma unroll
    for (int sm = 0; sm < 4; sm++)
#pragma unroll
        for (int sn = 0; sn < 4; sn++) {
            f32x4 v = acc[sm][sn];
#pragma unroll
            for (int reg = 0; reg < 4; reg++)
                C[(size_t)(row0 + sm * 16 + reg) * 256 + col0 + sn * 16] = v[reg];
        }

    // ---- fused BN stats: per-block column sums of the 128x128 C tile ----
    __syncthreads();
    if (tid < 128) { colsum[tid] = 0.f; colsq[tid] = 0.f; }
    __syncthreads();
#pragma unroll
    for (int sn = 0; sn < 4; sn++) {
        float sacc = 0.f, qacc = 0.f;
#pragma unroll
        for (int sm = 0; sm < 4; sm++) {
            f32x4 v = acc[sm][sn];
#pragma unroll
            for (int reg = 0; reg < 4; reg++) {
                sacc += v[reg];
                qacc += v[reg] * v[reg];
            }
        }
        int lc = cq * 64 + sn * 16 + m16;
        atomicAdd(&colsum[lc], sacc);
        atomicAdd(&colsq[lc], qacc);
    }
    __syncthreads();
    if (tid < 128) {
        atomicAdd(&gsum[bn + tid], colsum[tid]);
        atomicAdd(&gsq[bn + tid], colsq[tid]);
    }
}

__global__ void bn_finalize_kernel(
    const float* __restrict__ sum, const float* __restrict__ sumsq,
    const float* __restrict__ g, const float* __restrict__ bta, float invN,
    float* __restrict__ scale, float* __restrict__ shift)
{
    int c = threadIdx.x;
    float mean = sum[c] * invN;
    float var = sumsq[c] * invN - mean * mean;   // biased, matches torch BN
    float sc = g[c] * rsqrtf(var + 1e-5f);
    scale[c] = sc;
    shift[c] = bta[c] - mean * sc;
}

// ----------------------------- final: h2(ws) -> bn+relu -> d_out ----------
__global__ __launch_bounds__(256) void final_act_kernel(
    const float* __restrict__ h2, const float* __restrict__ scale,
    const float* __restrict__ shift, float* __restrict__ out, int total4)
{
    int i = blockIdx.x * 256 + threadIdx.x;
    if (i >= total4) return;
    int c4 = i & 63;
    float4 v = ((const float4*)h2)[i];
    float4 s = ((const float4*)scale)[c4];
    float4 t = ((const float4*)shift)[c4];
    float4 o;
    o.x = fmaxf(v.x * s.x + t.x, 0.0f);
    o.y = fmaxf(v.y * s.y + t.y, 0.0f);
    o.z = fmaxf(v.z * s.z + t.z, 0.0f);
    o.w = fmaxf(v.w * s.w + t.w, 0.0f);
    ((float4*)out)[i] = o;
}

// ------------------------------------------------------------------ launch --
extern "C" void kernel_launch(void* const* d_in, const int* in_sizes, int n_in,
                              void* d_out, int out_size, void* d_ws, size_t ws_size,
                              hipStream_t stream)
{
    const float* unknown = (const float*)d_in[0];
    const int*   ucnt    = (const int*)d_in[1];
    const float* known   = (const float*)d_in[2];
    const int*   kcnt    = (const int*)d_in[3];
    const float* ufeat   = (const float*)d_in[4];
    const float* kfeat   = (const float*)d_in[5];
    const float* W1      = (const float*)d_in[6];
    const float* g1      = (const float*)d_in[7];
    const float* b1      = (const float*)d_in[8];
    const float* W2      = (const float*)d_in[9];
    const float* g2      = (const float*)d_in[10];
    const float* b2      = (const float*)d_in[11];

    int N = in_sizes[0] / 3;        // 65536
    int B = in_sizes[1];            // 4

    char* ws = (char*)d_ws;
    size_t off = 0;
    float* wgt = (float*)(ws + off);            off += (size_t)N * 3 * 4;
    int*   idxb = (int*)(ws + off);             off += (size_t)N * 3 * 4;
    float* stats = (float*)(ws + off);          off += 8 * 256 * 4;
    float* sum1 = stats,         *sq1 = stats + 256;
    float* scale1 = stats + 512, *shift1 = stats + 768;
    float* sum2 = stats + 1024,  *sq2 = stats + 1280;
    float* scale2 = stats + 1536, *shift2 = stats + 1792;
    unsigned short* W1b = (unsigned short*)(ws + off);  off += 256 * 384 * 2;
    unsigned short* W2b = (unsigned short*)(ws + off);  off += 256 * 256 * 2;
    off = (off + 255) & ~(size_t)255;
    // big region: A1 (bf16 N*384 = 50.3MB) for gemm1, then reused as
    // h2 (fp32 N*256 = 67MB) for gemm2 output. Peak ws ~69MB (r2-proven size).
    unsigned short* A1 = (unsigned short*)(ws + off);
    float* h2 = (float*)(ws + off);
    float* h1 = (float*)d_out;                  // h1 lives in d_out

    hipMemsetAsync(stats, 0, 8 * 256 * 4, stream);

    knn3_kernel<<<N / 64, 256, 0, stream>>>(unknown, known, ucnt, kcnt,
                                            B, N, wgt, idxb);
    wconv_kernel<<<(256 * 384 + 256 * 256 + 255) / 256, 256, 0, stream>>>(
        W1, W2, W1b, W2b, 256 * 384, 256 * 256);
    build_a1_kernel<<<N / 4, 256, 0, stream>>>(wgt, idxb, kfeat, ufeat, A1, N);
    gemm_bf16_kernel<384, 0><<<dim3(N / 128, 2), 256, 0, stream>>>(
        A1, W1b, nullptr, nullptr, h1, sum1, sq1);
    bn_finalize_kernel<<<1, 256, 0, stream>>>(sum1, sq1, g1, b1, 1.0f / N,
                                              scale1, shift1);
    gemm_bf16_kernel<256, 1><<<dim3(N / 128, 2), 256, 0, stream>>>(
        h1, W2b, scale1, shift1, h2, sum2, sq2);
    bn_finalize_kernel<<<1, 256, 0, stream>>>(sum2, sq2, g2, b2, 1.0f / N,
                                              scale2, shift2);
    final_act_kernel<<<N / 4, 256, 0, stream>>>(h2, scale2, shift2,
                                                (float*)d_out, N * 64);
}

// Round 8
// 395.456 us; speedup vs baseline: 3.5397x; 1.0459x over previous
//
#include <hip/hip_runtime.h>
#include <math.h>

typedef __attribute__((ext_vector_type(8))) short short8;
typedef __attribute__((ext_vector_type(4))) float f32x4;

#define INF 3.0e38f

__device__ __forceinline__ unsigned short f2bf(float x) {
    union { float f; unsigned u; } v; v.f = x;
    unsigned r = v.u + 0x7FFF + ((v.u >> 16) & 1);   // RNE
    return (unsigned short)(r >> 16);
}

// ---------------------------------------------------------------- 3-NN ----
// Scalar-pipe scan: the candidate stream is wave-uniform, so known positions
// are loaded via SMEM (s_load) into SGPRs — no LDS staging, no barriers, no
// per-lane address math. Wave id pinned uniform via readfirstlane so the
// divergence analysis scalarizes the loads. Distance = 3 v_sub(SGPR) + 3 fma.
// Two-pass: pass 1 = top-3 values (5-op min/max net); merge -> thr; pass 2 =
// rescan, rare u64 (f32bits<<32|idx) lex insert when min4(e) <= thr.
// (k-u)^2 == (u-k)^2 bit-exact, so selection == lax.top_k semantics.
__global__ __launch_bounds__(256) void knn3_kernel(
    const float* __restrict__ unk, const float* __restrict__ kn,
    const int* __restrict__ ucnt, const int* __restrict__ kcnt,
    int B, int N, float* __restrict__ wgt, int* __restrict__ idxo)
{
    __shared__ float md[4][64][3];
    __shared__ float d2g[64];
    __shared__ unsigned long long mk[4][64][3];

    int tid = threadIdx.x;
    int s = __builtin_amdgcn_readfirstlane(tid >> 6);   // wave id, pinned SGPR
    int lane = tid & 63;
    int pbase = blockIdx.x * 64;
    int p = pbase + lane;

    int cum = 0, bb = 0;
    for (int i = 0; i < B; i++) { int c = ucnt[i]; if (pbase >= cum) bb = i; cum += c; }
    int kstart = 0;
    for (int i = 0; i < bb; i++) kstart += kcnt[i];
    int kend = kstart + kcnt[bb];

    float ux = unk[p * 3 + 0], uy = unk[p * 3 + 1], uz = unk[p * 3 + 2];

    int qlen = (kend - kstart) >> 2;            // uniform (4096/4 batches)
    int jbase = kstart + s * qlen;              // uniform per wave
    const float* kq = kn + (size_t)jbase * 3;   // uniform base -> s_load

    float d0 = INF, d1 = INF, d2 = INF;
    // 2 max + 3 min, no compares (d0<=d1<=d2 invariant)
    auto upd = [&](float e) {
        float m0 = fmaxf(e, d0);
        float m1 = fmaxf(e, d1);
        d0 = fminf(e, d0);
        d1 = fminf(m0, d1);
        d2 = fminf(m1, d2);
    };

    // ----------------- pass 1: top-3 values over own quarter -----------------
    for (int i = 0; i < qlen; i += 8) {
        float e[8];
#pragma unroll
        for (int c = 0; c < 8; c++) {
            float kx = kq[(i + c) * 3 + 0];     // uniform -> SGPR
            float ky = kq[(i + c) * 3 + 1];
            float kz = kq[(i + c) * 3 + 2];
            float dx = kx - ux, dy = ky - uy, dz = kz - uz;
            e[c] = __builtin_fmaf(dx, dx, __builtin_fmaf(dy, dy, dz * dz));
        }
#pragma unroll
        for (int c = 0; c < 8; c++) upd(e[c]);
    }

    md[s][lane][0] = d0; md[s][lane][1] = d1; md[s][lane][2] = d2;
    __syncthreads();
    if (tid < 64) {
        float v0 = INF, v1 = INF, v2 = INF;
#pragma unroll
        for (int w = 0; w < 4; w++)
#pragma unroll
            for (int k = 0; k < 3; k++) {
                float e = md[w][tid][k];
                float m0 = fmaxf(e, v0);
                float m1 = fmaxf(e, v1);
                v0 = fminf(e, v0);
                v1 = fminf(m0, v1);
                v2 = fminf(m1, v2);
            }
        d2g[tid] = v2;
    }
    __syncthreads();
    float thr = d2g[lane];

    // ----------------- pass 2: collect indices (rare path) ------------------
    unsigned long long s0 = ~0ULL, s1 = ~0ULL, s2 = ~0ULL;
    auto insK = [&](unsigned long long k) {
        bool c0 = k < s0;
        unsigned long long t0 = c0 ? k : s0;
        unsigned long long t1 = c0 ? s0 : k;
        bool c1 = t1 < s1;
        unsigned long long u0 = c1 ? t1 : s1;
        unsigned long long u1 = c1 ? s1 : t1;
        s0 = t0; s1 = u0;
        s2 = u1 < s2 ? u1 : s2;
    };
    auto mkkey = [](float e, int gj) {
        return ((unsigned long long)__float_as_uint(e) << 32) | (unsigned)gj;
    };

    for (int i = 0; i < qlen; i += 4) {
        float e[4];
#pragma unroll
        for (int c = 0; c < 4; c++) {
            float kx = kq[(i + c) * 3 + 0];
            float ky = kq[(i + c) * 3 + 1];
            float kz = kq[(i + c) * 3 + 2];
            float dx = kx - ux, dy = ky - uy, dz = kz - uz;
            e[c] = __builtin_fmaf(dx, dx, __builtin_fmaf(dy, dy, dz * dz));
        }
        float m4 = fminf(fminf(e[0], e[1]), fminf(e[2], e[3]));
        if (m4 <= thr) {
            int gj = jbase + i;
            insK(mkkey(e[0], gj + 0));
            insK(mkkey(e[1], gj + 1));
            insK(mkkey(e[2], gj + 2));
            insK(mkkey(e[3], gj + 3));
        }
    }

    mk[s][lane][0] = s0; mk[s][lane][1] = s1; mk[s][lane][2] = s2;
    __syncthreads();

    if (tid < 64) {
        s0 = s1 = s2 = ~0ULL;
#pragma unroll
        for (int qq = 0; qq < 4; qq++)
#pragma unroll
            for (int kk = 0; kk < 3; kk++)
                insK(mk[qq][tid][kk]);

        float dd0 = __uint_as_float((unsigned)(s0 >> 32));
        float dd1 = __uint_as_float((unsigned)(s1 >> 32));
        float dd2 = __uint_as_float((unsigned)(s2 >> 32));
        float r0 = 1.0f / (dd0 + 1e-8f);
        float r1 = 1.0f / (dd1 + 1e-8f);
        float r2 = 1.0f / (dd2 + 1e-8f);
        float rs = 1.0f / (r0 + r1 + r2);
        int pp = pbase + tid;
        wgt[pp * 3 + 0] = r0 * rs;
        wgt[pp * 3 + 1] = r1 * rs;
        wgt[pp * 3 + 2] = r2 * rs;
        idxo[pp * 3 + 0] = (int)(unsigned)s0;
        idxo[pp * 3 + 1] = (int)(unsigned)s1;
        idxo[pp * 3 + 2] = (int)(unsigned)s2;
    }
}

// --------------------------- build A1 = [interp | ufeat] as bf16 [N,384] --
__global__ __launch_bounds__(256) void build_a1_kernel(
    const float* __restrict__ wgt, const int* __restrict__ idxv,
    const float* __restrict__ kfeat, const float* __restrict__ ufeat,
    unsigned short* __restrict__ A1, int N)
{
    int t = blockIdx.x * 256 + threadIdx.x;
    int p = t >> 6, c4 = t & 63;
    if (p >= N) return;
    float w0 = wgt[p * 3 + 0], w1 = wgt[p * 3 + 1], w2 = wgt[p * 3 + 2];
    int j0 = idxv[p * 3 + 0], j1 = idxv[p * 3 + 1], j2 = idxv[p * 3 + 2];
    float4 v0 = ((const float4*)(kfeat + (size_t)j0 * 256))[c4];
    float4 v1 = ((const float4*)(kfeat + (size_t)j1 * 256))[c4];
    float4 v2 = ((const float4*)(kfeat + (size_t)j2 * 256))[c4];
    ushort4 ob;
    ob.x = f2bf(v0.x * w0 + v1.x * w1 + v2.x * w2);
    ob.y = f2bf(v0.y * w0 + v1.y * w1 + v2.y * w2);
    ob.z = f2bf(v0.z * w0 + v1.z * w1 + v2.z * w2);
    ob.w = f2bf(v0.w * w0 + v1.w * w1 + v2.w * w2);
    *(ushort4*)(A1 + (size_t)p * 384 + c4 * 4) = ob;
    float2 u = ((const float2*)(ufeat + (size_t)p * 128))[c4];
    ushort2 ub; ub.x = f2bf(u.x); ub.y = f2bf(u.y);
    *(ushort2*)(A1 + (size_t)p * 384 + 256 + c4 * 2) = ub;
}

// ------------------------------------------------ weight fp32->bf16 conv --
__global__ __launch_bounds__(256) void wconv_kernel(
    const float* __restrict__ W1, const float* __restrict__ W2,
    unsigned short* __restrict__ W1b, unsigned short* __restrict__ W2b,
    int n1, int n2)
{
    int i = blockIdx.x * 256 + threadIdx.x;
    if (i < n1) W1b[i] = f2bf(W1[i]);
    int j = i - n1;
    if (j >= 0 && j < n2) W2b[j] = f2bf(W2[j]);
}

// -------------------------------------------------------- bf16 MFMA GEMM --
// C[N,256] = A[N,K] x W[256,K]^T.  128x128 tile, BK=32, 16x16x32 MFMA.
// MODE 0: A is bf16 [N,K].
// MODE 1: A is fp32 [N,K]; staging applies relu(A*scale+shift) then bf16.
// Fused epilogue: per-block column sum/sumsq of C -> global atomics (BN stats).
template <int K, int MODE>
__global__ __launch_bounds__(256) void gemm_bf16_kernel(
    const void* __restrict__ Av, const unsigned short* __restrict__ W,
    const float* __restrict__ scale, const float* __restrict__ shift,
    float* __restrict__ C, float* __restrict__ gsum, float* __restrict__ gsq)
{
    __shared__ unsigned short As[128 * 40];
    __shared__ unsigned short Bs[128 * 40];
    __shared__ float colsum[128];
    __shared__ float colsq[128];

    int tid = threadIdx.x;
    int w = tid >> 6, lane = tid & 63;
    int r = w >> 1, cq = w & 1;
    int m16 = lane & 15, q = lane >> 4;
    int bm = blockIdx.x * 128, bn = blockIdx.y * 128;

    f32x4 acc[4][4];
#pragma unroll
    for (int i = 0; i < 4; i++)
#pragma unroll
        for (int j = 0; j < 4; j++) acc[i][j] = (f32x4){0.f, 0.f, 0.f, 0.f};

#pragma unroll
    for (int k0 = 0; k0 < K; k0 += 32) {
        __syncthreads();
#pragma unroll
        for (int i = 0; i < 2; i++) {
            int id = tid + i * 256;
            int row = id >> 2, kc = (id & 3) * 8;
            if (MODE == 0) {
                *(short8*)&As[row * 40 + kc] =
                    *(const short8*)((const unsigned short*)Av +
                                     (size_t)(bm + row) * K + k0 + kc);
            } else {
                const float* Af = (const float*)Av;
                float4 v0 = *(const float4*)(Af + (size_t)(bm + row) * K + k0 + kc);
                float4 v1 = *(const float4*)(Af + (size_t)(bm + row) * K + k0 + kc + 4);
                float4 s0 = *(const float4*)(scale + k0 + kc);
                float4 s1 = *(const float4*)(scale + k0 + kc + 4);
                float4 t0 = *(const float4*)(shift + k0 + kc);
                float4 t1 = *(const float4*)(shift + k0 + kc + 4);
                ushort4 o0, o1;
                o0.x = f2bf(fmaxf(v0.x * s0.x + t0.x, 0.f));
                o0.y = f2bf(fmaxf(v0.y * s0.y + t0.y, 0.f));
                o0.z = f2bf(fmaxf(v0.z * s0.z + t0.z, 0.f));
                o0.w = f2bf(fmaxf(v0.w * s0.w + t0.w, 0.f));
                o1.x = f2bf(fmaxf(v1.x * s1.x + t1.x, 0.f));
                o1.y = f2bf(fmaxf(v1.y * s1.y + t1.y, 0.f));
                o1.z = f2bf(fmaxf(v1.z * s1.z + t1.z, 0.f));
                o1.w = f2bf(fmaxf(v1.w * s1.w + t1.w, 0.f));
                *(ushort4*)&As[row * 40 + kc] = o0;
                *(ushort4*)&As[row * 40 + kc + 4] = o1;
            }
            *(short8*)&Bs[row * 40 + kc] =
                *(const short8*)(W + (size_t)(bn + row) * K + k0 + kc);
        }
        __syncthreads();

        short8 af[4], bf[4];
#pragma unroll
        for (int sub = 0; sub < 4; sub++) {
            af[sub] = *(const short8*)&As[(r * 64 + sub * 16 + m16) * 40 + q * 8];
            bf[sub] = *(const short8*)&Bs[(cq * 64 + sub * 16 + m16) * 40 + q * 8];
        }
#pragma unroll
        for (int sm = 0; sm < 4; sm++)
#pragma unroll
            for (int sn = 0; sn < 4; sn++)
                acc[sm][sn] = __builtin_amdgcn_mfma_f32_16x16x32_bf16(
                    af[sm], bf[sn], acc[sm][sn], 0, 0, 0);
    }

    int row0 = bm + r * 64 + q * 4;
    int col0 = bn + cq * 64 + m16;
#pragma unroll
    for (int sm = 0; sm < 4; sm++)
#pragma unroll
        for (int sn = 0; sn < 4; sn++) {
            f32x4 v = acc[sm][sn];
#pragma unroll
            for (int reg = 0; reg < 4; reg++)
                C[(size_t)(row0 + sm * 16 + reg) * 256 + col0 + sn * 16] = v[reg];
        }

    // ---- fused BN stats: per-block column sums of the 128x128 C tile ----
    __syncthreads();
    if (tid < 128) { colsum[tid] = 0.f; colsq[tid] = 0.f; }
    __syncthreads();
#pragma unroll
    for (int sn = 0; sn < 4; sn++) {
        float sacc = 0.f, qacc = 0.f;
#pragma unroll
        for (int sm = 0; sm < 4; sm++) {
            f32x4 v = acc[sm][sn];
#pragma unroll
            for (int reg = 0; reg < 4; reg++) {
                sacc += v[reg];
                qacc += v[reg] * v[reg];
            }
        }
        int lc = cq * 64 + sn * 16 + m16;
        atomicAdd(&colsum[lc], sacc);
        atomicAdd(&colsq[lc], qacc);
    }
    __syncthreads();
    if (tid < 128) {
        atomicAdd(&gsum[bn + tid], colsum[tid]);
        atomicAdd(&gsq[bn + tid], colsq[tid]);
    }
}

__global__ void bn_finalize_kernel(
    const float* __restrict__ sum, const float* __restrict__ sumsq,
    const float* __restrict__ g, const float* __restrict__ bta, float invN,
    float* __restrict__ scale, float* __restrict__ shift)
{
    int c = threadIdx.x;
    float mean = sum[c] * invN;
    float var = sumsq[c] * invN - mean * mean;   // biased, matches torch BN
    float sc = g[c] * rsqrtf(var + 1e-5f);
    scale[c] = sc;
    shift[c] = bta[c] - mean * sc;
}

// ----------------------------- final: h2(ws) -> bn+relu -> d_out ----------
__global__ __launch_bounds__(256) void final_act_kernel(
    const float* __restrict__ h2, const float* __restrict__ scale,
    const float* __restrict__ shift, float* __restrict__ out, int total4)
{
    int i = blockIdx.x * 256 + threadIdx.x;
    if (i >= total4) return;
    int c4 = i & 63;
    float4 v = ((const float4*)h2)[i];
    float4 s = ((const float4*)scale)[c4];
    float4 t = ((const float4*)shift)[c4];
    float4 o;
    o.x = fmaxf(v.x * s.x + t.x, 0.0f);
    o.y = fmaxf(v.y * s.y + t.y, 0.0f);
    o.z = fmaxf(v.z * s.z + t.z, 0.0f);
    o.w = fmaxf(v.w * s.w + t.w, 0.0f);
    ((float4*)out)[i] = o;
}

// ------------------------------------------------------------------ launch --
extern "C" void kernel_launch(void* const* d_in, const int* in_sizes, int n_in,
                              void* d_out, int out_size, void* d_ws, size_t ws_size,
                              hipStream_t stream)
{
    const float* unknown = (const float*)d_in[0];
    const int*   ucnt    = (const int*)d_in[1];
    const float* known   = (const float*)d_in[2];
    const int*   kcnt    = (const int*)d_in[3];
    const float* ufeat   = (const float*)d_in[4];
    const float* kfeat   = (const float*)d_in[5];
    const float* W1      = (const float*)d_in[6];
    const float* g1      = (const float*)d_in[7];
    const float* b1      = (const float*)d_in[8];
    const float* W2      = (const float*)d_in[9];
    const float* g2      = (const float*)d_in[10];
    const float* b2      = (const float*)d_in[11];

    int N = in_sizes[0] / 3;        // 65536
    int B = in_sizes[1];            // 4

    char* ws = (char*)d_ws;
    size_t off = 0;
    float* wgt = (float*)(ws + off);            off += (size_t)N * 3 * 4;
    int*   idxb = (int*)(ws + off);             off += (size_t)N * 3 * 4;
    float* stats = (float*)(ws + off);          off += 8 * 256 * 4;
    float* sum1 = stats,         *sq1 = stats + 256;
    float* scale1 = stats + 512, *shift1 = stats + 768;
    float* sum2 = stats + 1024,  *sq2 = stats + 1280;
    float* scale2 = stats + 1536, *shift2 = stats + 1792;
    unsigned short* W1b = (unsigned short*)(ws + off);  off += 256 * 384 * 2;
    unsigned short* W2b = (unsigned short*)(ws + off);  off += 256 * 256 * 2;
    off = (off + 255) & ~(size_t)255;
    // big region: A1 (bf16 N*384 = 50.3MB) for gemm1, then reused as
    // h2 (fp32 N*256 = 67MB) for gemm2 output. Peak ws ~69MB (r2-proven size).
    unsigned short* A1 = (unsigned short*)(ws + off);
    float* h2 = (float*)(ws + off);
    float* h1 = (float*)d_out;                  // h1 lives in d_out

    hipMemsetAsync(stats, 0, 8 * 256 * 4, stream);

    knn3_kernel<<<N / 64, 256, 0, stream>>>(unknown, known, ucnt, kcnt,
                                            B, N, wgt, idxb);
    wconv_kernel<<<(256 * 384 + 256 * 256 + 255) / 256, 256, 0, stream>>>(
        W1, W2, W1b, W2b, 256 * 384, 256 * 256);
    build_a1_kernel<<<N / 4, 256, 0, stream>>>(wgt, idxb, kfeat, ufeat, A1, N);
    gemm_bf16_kernel<384, 0><<<dim3(N / 128, 2), 256, 0, stream>>>(
        A1, W1b, nullptr, nullptr, h1, sum1, sq1);
    bn_finalize_kernel<<<1, 256, 0, stream>>>(sum1, sq1, g1, b1, 1.0f / N,
                                              scale1, shift1);
    gemm_bf16_kernel<256, 1><<<dim3(N / 128, 2), 256, 0, stream>>>(
        h1, W2b, scale1, shift1, h2, sum2, sq2);
    bn_finalize_kernel<<<1, 256, 0, stream>>>(sum2, sq2, g2, b2, 1.0f / N,
                                              scale2, shift2);
    final_act_kernel<<<N / 4, 256, 0, stream>>>(h2, scale2, shift2,
                                                (float*)d_out, N * 64);
}